// Round 5
// baseline (225.385 us; speedup 1.0000x reference)
//
#include <hip/hip_runtime.h>
#include <hip/hip_bf16.h>
#include <stdint.h>

typedef __bf16 bf16;
typedef __bf16 bf16x8 __attribute__((ext_vector_type(8)));
typedef __bf16 bf16x4 __attribute__((ext_vector_type(4)));
typedef float  f32x4  __attribute__((ext_vector_type(4)));
typedef float  f32x16 __attribute__((ext_vector_type(16)));

#define S_LEN  2048
#define NH     16
#define DKV    64
#define DMODEL 1024
#define LOG2E  1.4426950408889634f

// raw barrier + counted waits: keep loads in flight across barriers (T3/T4).
#define SBAR()       __builtin_amdgcn_s_barrier()
#define SFENCE()     __builtin_amdgcn_sched_barrier(0)
#define WAIT_VM(N)   asm volatile("s_waitcnt vmcnt(" #N ")" ::: "memory")
#define WAIT_LGKM0() asm volatile("s_waitcnt lgkmcnt(0)" ::: "memory")

// ---------------------------------------------------------------------------
// async global->LDS 16B copy. LDS dest is wave-uniform base + lane*16.
// ---------------------------------------------------------------------------
__device__ __forceinline__ void async_load16(const void* g, void* l) {
  __builtin_amdgcn_global_load_lds(
      (const __attribute__((address_space(1))) uint32_t*)(uintptr_t)g,
      (__attribute__((address_space(3))) uint32_t*)(uintptr_t)l,
      16, 0, 0);
}

// ---------------------------------------------------------------------------
// Transpose-cast W [K=1024][N=1024] fp32 -> Wt bf16 [N][K].
// v2: 64x64 tiles, vectorized global I/O (f32x4 loads, bf16x8 stores).
// grid (16,16,4), block 256.
// ---------------------------------------------------------------------------
__global__ void transpose_w(const float* __restrict__ W0, const float* __restrict__ W1,
                            const float* __restrict__ W2, const float* __restrict__ W3,
                            bf16* __restrict__ T0, bf16* __restrict__ T1,
                            bf16* __restrict__ T2, bf16* __restrict__ T3)
{
  int z = blockIdx.z;
  const float* W = (z == 0) ? W0 : (z == 1) ? W1 : (z == 2) ? W2 : W3;
  bf16* T = (z == 0) ? T0 : (z == 1) ? T1 : (z == 2) ? T2 : T3;
  __shared__ float tile[64][65];         // +1 pad: write-phase reads 2-way max
  int n0 = blockIdx.x * 64, k0 = blockIdx.y * 64;
  int tid = threadIdx.x;

  // load: rows k0..k0+63 x cols n0..n0+63, f32x4 coalesced (256B/row-wave)
  int c4 = (tid & 15) * 4;
  int rr = tid >> 4;                     // 0..15
  for (int g = 0; g < 4; ++g) {
    int k = g * 16 + rr;
    f32x4 v = *(const f32x4*)(W + (size_t)(k0 + k) * DMODEL + n0 + c4);
    tile[k][c4] = v[0]; tile[k][c4 + 1] = v[1];
    tile[k][c4 + 2] = v[2]; tile[k][c4 + 3] = v[3];
  }
  __syncthreads();

  // store: T row n = 64 bf16 = 8 lanes x bf16x8 (128B/row)
  int kc = tid & 7, rn2 = tid >> 3;      // rn2 0..31
  for (int pass = 0; pass < 2; ++pass) {
    int rn = pass * 32 + rn2;
    bf16x8 o;
    for (int w = 0; w < 8; ++w) o[w] = (bf16)tile[kc * 8 + w][rn];
    *(bf16x8*)(T + (size_t)(n0 + rn) * DMODEL + k0 + kc * 8) = o;
  }
}

// ---------------------------------------------------------------------------
// QKV GEMM: fused fp32->bf16 cast on A; 128x128 tile, BK=64. (round-4 winner,
// unchanged except z==2 epilogue writes the NEW vperm layout [bh][tile][p][d][8]
// so attn PV can read one contiguous b128 per fragment.)
// grid (m=32, n=8, z=3) = 768 blocks = 3/CU; LDS 48KB.
// ---------------------------------------------------------------------------
__global__ __launch_bounds__(256) void gemm_qkv(
    const float* __restrict__ Aq, const float* __restrict__ Ak, const float* __restrict__ Av,
    const bf16* __restrict__ Bq, const bf16* __restrict__ Bk, const bf16* __restrict__ Bv,
    bf16* __restrict__ Cq, bf16* __restrict__ Ck, bf16* __restrict__ Cv)
{
  __shared__ __align__(16) char smem[49152];   // As 16K [128][64] + Bs0/Bs1 16K each
  bf16* As  = (bf16*)smem;
  bf16* Bs0 = (bf16*)(smem + 16384);
  bf16* Bs1 = (bf16*)(smem + 32768);
  bf16* Ls  = (bf16*)smem;               // epilogue overlay [128][132] = 33.8KB

  const int z = blockIdx.z;
  const float* A = (z == 0) ? Aq : (z == 1) ? Ak : Av;
  const bf16* Bt = (z == 0) ? Bq : (z == 1) ? Bk : Bv;
  bf16* C        = (z == 0) ? Cq : (z == 1) ? Ck : Cv;

  const int m0 = blockIdx.x * 128;       // m on x: XCD-local A reuse
  const int n0 = blockIdx.y * 128;
  const int tid = threadIdx.x;
  const int lane = tid & 63;
  const int wave = tid >> 6;
  const int wm = (wave >> 1) * 64;       // wave output: 64x64
  const int wn = (wave & 1) * 64;
  const int row = lane & 15;
  const int quad = lane >> 4;

  f32x4 acc[4][4];
  for (int i = 0; i < 4; ++i)
    for (int j = 0; j < 4; ++j) acc[i][j] = (f32x4){0.f, 0.f, 0.f, 0.f};

  const int arc = tid & 7;
  const int arr = tid >> 3;              // 0..31
  const float* Ap0 = A + (size_t)(m0 +  0 + arr) * DMODEL + arc * 8;
  const float* Ap1 = A + (size_t)(m0 + 32 + arr) * DMODEL + arc * 8;
  const float* Ap2 = A + (size_t)(m0 + 64 + arr) * DMODEL + arc * 8;
  const float* Ap3 = A + (size_t)(m0 + 96 + arr) * DMODEL + arc * 8;

  auto stageB = [&](int kt, bf16* Bsel) {
    const int kk = kt << 6;
    for (int j = 0; j < 4; ++j) {
      int base = j * 256 + wave * 64;
      int idx = base + lane;
      int r = idx >> 3;
      int cc = (idx & 7) ^ (r & 7);
      async_load16(Bt + (size_t)(n0 + r) * DMODEL + kk + cc * 8,
                   (char*)Bsel + (size_t)base * 16);
    }
  };

  f32x4 av[4][2];
  av[0][0] = *(const f32x4*)(Ap0); av[0][1] = *(const f32x4*)(Ap0 + 4);
  av[1][0] = *(const f32x4*)(Ap1); av[1][1] = *(const f32x4*)(Ap1 + 4);
  av[2][0] = *(const f32x4*)(Ap2); av[2][1] = *(const f32x4*)(Ap2 + 4);
  av[3][0] = *(const f32x4*)(Ap3); av[3][1] = *(const f32x4*)(Ap3 + 4);
  SFENCE();
  stageB(0, Bs0);
  SFENCE();

  for (int kt = 0; kt < 16; ++kt) {
    bf16* Bcur = (kt & 1) ? Bs1 : Bs0;
    bf16* Bnxt = (kt & 1) ? Bs0 : Bs1;
    if (kt < 15) stageB(kt + 1, Bnxt);
#pragma unroll
    for (int g = 0; g < 4; ++g) {
      bf16x8 o;
      for (int w = 0; w < 4; ++w) { o[w] = (bf16)av[g][0][w]; o[w + 4] = (bf16)av[g][1][w]; }
      int r = g * 32 + arr;              // (r&7)==(arr&7)
      *(bf16x8*)(As + r * 64 + ((arc ^ (arr & 7)) << 3)) = o;
    }
    if (kt < 15) {
      const int kn = (kt + 1) << 6;
      av[0][0] = *(const f32x4*)(Ap0 + kn); av[0][1] = *(const f32x4*)(Ap0 + kn + 4);
      av[1][0] = *(const f32x4*)(Ap1 + kn); av[1][1] = *(const f32x4*)(Ap1 + kn + 4);
      av[2][0] = *(const f32x4*)(Ap2 + kn); av[2][1] = *(const f32x4*)(Ap2 + kn + 4);
      av[3][0] = *(const f32x4*)(Ap3 + kn); av[3][1] = *(const f32x4*)(Ap3 + kn + 4);
    }
    SFENCE();
    if (kt < 15) { WAIT_VM(12); }        // guard: B(kt+1)4 + av(kt+1)8 in flight
    else         { WAIT_VM(0); }
    WAIT_LGKM0();
    SBAR();
    SFENCE();
    for (int ks = 0; ks < 2; ++ks) {
      bf16x8 af[4], bfr[4];
      for (int i = 0; i < 4; ++i) {
        int rr = wm + i * 16 + row;
        af[i] = *(const bf16x8*)(As + rr * 64 + (((quad + ks * 4) ^ (rr & 7)) << 3));
      }
      for (int j = 0; j < 4; ++j) {
        int rr = wn + j * 16 + row;
        bfr[j] = *(const bf16x8*)(Bcur + rr * 64 + (((quad + ks * 4) ^ (rr & 7)) << 3));
      }
      for (int i = 0; i < 4; ++i)
        for (int j = 0; j < 4; ++j)
          acc[i][j] = __builtin_amdgcn_mfma_f32_16x16x32_bf16(af[i], bfr[j], acc[i][j], 0, 0, 0);
    }
    SFENCE();
    SBAR();
  }

  if (z != 2) {
    const int bq = m0 >> 11;
    __syncthreads();
    for (int i = 0; i < 4; ++i)
      for (int j = 0; j < 4; ++j)
        for (int r = 0; r < 4; ++r)
          Ls[(wm + i * 16 + quad * 4 + r) * 132 + wn + j * 16 + row] = (bf16)acc[i][j][r];
    __syncthreads();
    for (int u = 0; u < 8; ++u) {
      int cc = u * 256 + tid;
      int rloc = cc >> 4, c8 = (cc & 15) * 8;
      int s = (m0 + rloc) & 2047;
      int gn = n0 + c8;
      int h = gn >> 6, d = gn & 63;
      bf16x8 val = *(const bf16x8*)(Ls + rloc * 132 + c8);
      *(bf16x8*)(C + (((size_t)(bq * NH + h)) * S_LEN + s) * DKV + d) = val;
    }
  } else {
    // V permuted for attn PV (NEW): [bh][tile=s/64][p][d][slot(8)]
    //   kb=(s&63)>>2, half=(kb>>1)&1, p=(kb&1)+2*((kb>>2)&1)+4*(kb>>3),
    //   slot = half*4 + (s&3). Reader gets {kb0, kb0+2} pairs contiguously.
    for (int i = 0; i < 4; ++i)
      for (int j = 0; j < 4; ++j) {
        int gm = m0 + wm + i * 16 + quad * 4;    // s base (r=0..3 consecutive)
        int gn = n0 + wn + j * 16 + row;
        int b = gm >> 11, s = gm & 2047;
        int h = gn >> 6,  d = gn & 63;
        int bh = b * NH + h;
        int tile = s >> 6, kb = (s & 63) >> 2;
        int half = (kb >> 1) & 1;
        int p = (kb & 1) + ((kb >> 2) & 1) * 2 + (kb >> 3) * 4;
        bf16x4 t;
        for (int r = 0; r < 4; ++r) t[r] = (bf16)acc[i][j][r];
        *(bf16x4*)(C + ((((size_t)bh * 32 + tile) * 8 + p) * 64 + d) * 8 + half * 4) = t;
      }
  }
}

// ---------------------------------------------------------------------------
// Flash attention: S^T = K*Q^T via 32x32x16 MFMA; P stays in registers.
// v3: PV B-fragment = ONE contiguous ds_read_b128 (new vperm layout) --
// removes 16 b64 reads + pack movs/iter and the even-bank-only conflict
// pattern; Sm init from pinned zero regs (no per-iter 32 v_movs).
// grid (bh=32, q=16, zh=2); LDS 33KB.
// ---------------------------------------------------------------------------
__global__ __launch_bounds__(256, 4) void attn_kernel(
    const bf16* __restrict__ Qh, const bf16* __restrict__ Kh, const bf16* __restrict__ Vperm,
    const float* __restrict__ mask, bf16* __restrict__ Opart, float* __restrict__ Lpart)
{
  __shared__ __align__(16) bf16 Ks[2][64 * 64];    // [kv][d], chunk XOR-swizzled
  __shared__ __align__(16) bf16 Vts[2][64 * 64];   // [p][d][8] (new layout)
  __shared__ __align__(16) float masks2[2][64];

  const int bh = blockIdx.x;
  const int b = bh >> 4;
  const int q0 = blockIdx.y * 128;
  const int zh = blockIdx.z;
  const int tid = threadIdx.x;
  const int lane = tid & 63;
  const int wave = tid >> 6;
  const int ln = lane & 31;
  const int hi = lane >> 5;
  const float SC2 = 0.125f * LOG2E;

  // pinned zero accumulator seed (opaque so init hoists out of the loop)
  float zseed;
  asm volatile("v_mov_b32 %0, 0" : "=v"(zseed));
  f32x16 z16;
  for (int i = 0; i < 16; ++i) z16[i] = zseed;

  const int qg = q0 + wave * 32 + ln;
  bf16x8 qf[4];
  {
    const bf16* qrow = Qh + ((size_t)bh * S_LEN + qg) * DKV;
    for (int c = 0; c < 4; ++c)
      qf[c] = *(const bf16x8*)(qrow + c * 16 + hi * 8);
  }

  auto stage = [&](int it, int buf) {
    const int kv0 = zh * 1024 + it * 64;
    float mval = 0.f;
    if (tid < 64) mval = mask[b * S_LEN + kv0 + tid];   // issued first
    const bf16* vtile = Vperm + ((size_t)bh * 32 + (kv0 >> 6)) * 4096;
    for (int j = 0; j < 2; ++j) {
      int base = j * 256 + wave * 64;
      int idx = base + lane;
      int r = idx >> 3;
      int cc = (idx & 7) ^ (r & 7);
      async_load16(Kh + ((size_t)bh * S_LEN + kv0 + r) * DKV + cc * 8,
                   (char*)Ks[buf] + (size_t)base * 16);
      async_load16(vtile + (size_t)idx * 8,
                   (char*)Vts[buf] + (size_t)base * 16);
    }
    if (tid < 64) masks2[buf][tid] = mval * LOG2E;
  };

  f32x16 O[2];
  for (int nb = 0; nb < 2; ++nb)
    for (int i = 0; i < 16; ++i) O[nb][i] = 0.f;
  float lsum = 0.f;

  stage(0, 0);                                  // prologue

  for (int it = 0; it < 16; ++it) {
    const int cur = it & 1;
    if (it < 15) stage(it + 1, cur ^ 1);
    SFENCE();
    if (it < 15) { WAIT_VM(4); }                // KV(it) landed; KV(it+1) in flight
    else         { WAIT_VM(0); }
    WAIT_LGKM0();
    SBAR();
    SFENCE();

    // S^T = K * Q^T; c=0 seeds from pinned zeros (no per-iter acc zeroing)
    f32x16 Sm[2];
    {
      bf16x8 k0 = *(const bf16x8*)(Ks[cur] + ln * 64        + ((hi ^ (ln & 7)) << 3));
      bf16x8 k1 = *(const bf16x8*)(Ks[cur] + (32 + ln) * 64 + ((hi ^ (ln & 7)) << 3));
      Sm[0] = __builtin_amdgcn_mfma_f32_32x32x16_bf16(k0, qf[0], z16, 0, 0, 0);
      Sm[1] = __builtin_amdgcn_mfma_f32_32x32x16_bf16(k1, qf[0], z16, 0, 0, 0);
    }
    for (int c = 1; c < 4; ++c) {
      bf16x8 k0 = *(const bf16x8*)(Ks[cur] + ln * 64        + (((2 * c + hi) ^ (ln & 7)) << 3));
      bf16x8 k1 = *(const bf16x8*)(Ks[cur] + (32 + ln) * 64 + (((2 * c + hi) ^ (ln & 7)) << 3));
      Sm[0] = __builtin_amdgcn_mfma_f32_32x32x16_bf16(k0, qf[c], Sm[0], 0, 0, 0);
      Sm[1] = __builtin_amdgcn_mfma_f32_32x32x16_bf16(k1, qf[c], Sm[1], 0, 0, 0);
    }

    // P = exp2(S*SC2 + mask*LOG2E) in registers -> PV (one b128 per fragment)
    for (int cg = 0; cg < 4; ++cg) {
      int mb = cg >> 1, g = cg & 1;
      int koff = 32 * mb + 16 * g + 4 * hi;
      f32x4 mklo = *(const f32x4*)(&masks2[cur][koff]);
      f32x4 mkhi = *(const f32x4*)(&masks2[cur][koff + 8]);
      bf16x8 ap;
      float ls0 = 0.f;
      for (int u = 0; u < 4; ++u) {
        float p = __builtin_amdgcn_exp2f(Sm[mb][g * 8 + u] * SC2 + mklo[u]);
        ls0 += p; ap[u] = (bf16)p;
      }
      for (int u = 0; u < 4; ++u) {
        float p = __builtin_amdgcn_exp2f(Sm[mb][g * 8 + 4 + u] * SC2 + mkhi[u]);
        ls0 += p; ap[4 + u] = (bf16)p;
      }
      lsum += ls0;
      int p = hi + 2 * g + 4 * mb;              // pair index in new V layout
      for (int nb = 0; nb < 2; ++nb) {
        int d = nb * 32 + ln;
        bf16x8 bv = *(const bf16x8*)(Vts[cur] + ((size_t)p * 64 + d) * 8);
        O[nb] = __builtin_amdgcn_mfma_f32_32x32x16_bf16(ap, bv, O[nb], 0, 0, 0);
      }
    }
    SFENCE();
    SBAR();
  }

  // partial row sums
  float lt = lsum + __shfl_xor(lsum, 32, 64);
  if (lane < 32)
    Lpart[((size_t)zh * 32 + bh) * S_LEN + q0 + wave * 32 + ln] = lt;

  // partial O (un-normalized, bf16): Opart[zh][bh][q][d]
  bf16* ob = Opart + (((size_t)zh * 32 + bh) * S_LEN) * DKV;
  for (int g = 0; g < 4; ++g)
    for (int nb = 0; nb < 2; ++nb)
      for (int j = 0; j < 4; ++j) {
        int qrow = q0 + wave * 32 + j + 8 * g + 4 * hi;
        ob[(size_t)qrow * DKV + nb * 32 + ln] = (bf16)O[nb][g * 4 + j];
      }
}

// ---------------------------------------------------------------------------
// Out-GEMM v2: 64x128 tile (was 32x128 -- 8 MFMA per 12 b128 reads was the
// LDS-issue-bound 64^2 regime). Wave output 32x64 -> 16 MFMA / 12 b128.
// Fused combine+normalize on A; depth-1 Opart reg prefetch; B dbuf + counted
// vmcnt. Ledger: steady entering iter kt = [B(kt)4, h(kt)4]; +B(kt+1) ->
// cvt's auto vmcnt(4) retires B(kt)+h(kt) -> +h(kt+1) -> WAIT_VM(8) no-op
// guard. Tail kt=15 drains.
// grid (m=64, n=8) = 512 blocks -> 2/CU; LDS 45KB.
// ---------------------------------------------------------------------------
__global__ __launch_bounds__(256) void gemm_out(
    const bf16* __restrict__ Opart, const float* __restrict__ Lpart,
    const bf16* __restrict__ Wot, float* __restrict__ Cout)
{
  __shared__ __align__(16) bf16 As[64 * 64];       // 8KB swizzled
  __shared__ __align__(16) bf16 Bs[2][128 * 64];   // 32KB swizzled, dbuf
  __shared__ float rinv[NH * 64];                  // 4KB

  const int m0 = blockIdx.x * 64;        // m on x: XCD-local Opart reuse
  const int n0 = blockIdx.y * 128;
  const int tid = threadIdx.x;
  const int lane = tid & 63;
  const int wave = tid >> 6;
  const int wm = (wave >> 1) * 32;
  const int wn = (wave & 1) * 64;
  const int row = lane & 15;
  const int quad = lane >> 4;
  const int b = m0 >> 11;
  const int s0 = m0 & 2047;

  // per-block row-sum reciprocals: all 16 heads x 64 rows
  for (int u = 0; u < 4; ++u) {
    int idx = u * 256 + tid;
    int h = idx >> 6, r = idx & 63;
    float l = Lpart[(size_t)(b * NH + h) * S_LEN + s0 + r]
            + Lpart[(size_t)(32 + b * NH + h) * S_LEN + s0 + r];
    rinv[idx] = 1.0f / l;
  }
  SFENCE();                              // rinv loads fully retired before prologue

  f32x4 acc[2][4];
  for (int i = 0; i < 2; ++i)
    for (int j = 0; j < 4; ++j) acc[i][j] = (f32x4){0.f, 0.f, 0.f, 0.f};

  const int arc = tid & 7;               // chunk col
  const int arr = tid >> 3;              // row 0..31 (second row adds 32)
  const size_t HSTEP = (size_t)S_LEN * DKV;        // per-head stride
  const size_t ZSTEP = (size_t)32 * S_LEN * DKV;   // zh stride
  const bf16* Oa = Opart + ((size_t)(b * NH) * S_LEN + s0 + arr) * DKV + arc * 8;
  const bf16* Ob = Oa + (size_t)32 * DKV;          // row arr+32

  auto stageB = [&](int kt, int buf) {
    for (int j = 0; j < 4; ++j) {
      int base = j * 256 + wave * 64;
      int idx = base + lane;
      int r = idx >> 3;
      int cc = (idx & 7) ^ (r & 7);
      async_load16(Wot + (size_t)(n0 + r) * DMODEL + kt * 64 + cc * 8,
                   (char*)Bs[buf] + (size_t)base * 16);
    }
  };

  // prologue: h(0)[4] -> B(0)[4]
  bf16x8 h00 = *(const bf16x8*)(Oa);
  bf16x8 h01 = *(const bf16x8*)(Oa + ZSTEP);
  bf16x8 h10 = *(const bf16x8*)(Ob);
  bf16x8 h11 = *(const bf16x8*)(Ob + ZSTEP);
  SFENCE();
  stageB(0, 0);
  SFENCE();
  WAIT_LGKM0();                          // rinv ds_writes visible
  SBAR();                                // publish rinv (no vmcnt drain)

  for (int kt = 0; kt < 16; ++kt) {      // kt == head index (BK=64 == DKV)
    const int cur = kt & 1;
    if (kt < 15) stageB(kt + 1, cur ^ 1);
    {
      float rv  = rinv[kt * 64 + arr];
      float rv2 = rinv[kt * 64 + 32 + arr];
      bf16x8 o;
      for (int w = 0; w < 8; ++w)
        o[w] = (bf16)(((float)h00[w] + (float)h01[w]) * rv);
      *(bf16x8*)(As + arr * 64 + ((arc ^ (arr & 7)) << 3)) = o;
      for (int w = 0; w < 8; ++w)
        o[w] = (bf16)(((float)h10[w] + (float)h11[w]) * rv2);
      *(bf16x8*)(As + (32 + arr) * 64 + ((arc ^ (arr & 7)) << 3)) = o;  // (32+arr)&7==arr&7
    }
    if (kt < 15) {                       // prefetch h(kt+1) during MFMA
      const size_t off = (size_t)(kt + 1) * HSTEP;
      h00 = *(const bf16x8*)(Oa + off);
      h01 = *(const bf16x8*)(Oa + off + ZSTEP);
      h10 = *(const bf16x8*)(Ob + off);
      h11 = *(const bf16x8*)(Ob + off + ZSTEP);
    }
    SFENCE();
    if (kt < 15) { WAIT_VM(8); }         // B(kt+1)4 + h(kt+1)4 in flight
    else         { WAIT_VM(0); }
    WAIT_LGKM0();
    SBAR();
    SFENCE();
    for (int ks = 0; ks < 2; ++ks) {
      bf16x8 af[2], bfr[4];
      for (int i = 0; i < 2; ++i) {
        int rr = wm + i * 16 + row;
        af[i] = *(const bf16x8*)(As + rr * 64 + (((quad + ks * 4) ^ (rr & 7)) << 3));
      }
      for (int j = 0; j < 4; ++j) {
        int rr = wn + j * 16 + row;
        bfr[j] = *(const bf16x8*)(Bs[cur] + rr * 64 + (((quad + ks * 4) ^ (rr & 7)) << 3));
      }
      for (int i = 0; i < 2; ++i)
        for (int j = 0; j < 4; ++j)
          acc[i][j] = __builtin_amdgcn_mfma_f32_16x16x32_bf16(af[i], bfr[j], acc[i][j], 0, 0, 0);
    }
    SFENCE();
    SBAR();
  }

  for (int i = 0; i < 2; ++i)
    for (int j = 0; j < 4; ++j)
      for (int r = 0; r < 4; ++r) {
        int gm = m0 + wm + i * 16 + quad * 4 + r;
        int gn = n0 + wn + j * 16 + row;
        Cout[(size_t)gm * DMODEL + gn] = acc[i][j][r];
      }
}

// ---------------------------------------------------------------------------
extern "C" void kernel_launch(void* const* d_in, const int* in_sizes, int n_in,
                              void* d_out, int out_size, void* d_ws, size_t ws_size,
                              hipStream_t stream)
{
  const float* query = (const float*)d_in[0];
  const float* key_  = (const float*)d_in[1];
  const float* value = (const float*)d_in[2];
  const float* mask  = (const float*)d_in[3];
  const float* Wq = (const float*)d_in[4];
  const float* Wk = (const float*)d_in[5];
  const float* Wv = (const float*)d_in[6];
  const float* Wo = (const float*)d_in[7];

  char* ws = (char*)d_ws;
  const size_t MB = (size_t)1 << 20;
  bf16* qh    = (bf16*)(ws + 0 * MB);    // 8MB [B,NH,S,DKV]
  bf16* kh    = (bf16*)(ws + 8 * MB);    // 8MB [B,NH,S,DKV]
  bf16* vperm = (bf16*)(ws + 16 * MB);   // 8MB PV-permuted V (new layout)
  bf16* wot   = (bf16*)(ws + 24 * MB);   // 2MB (live until out-GEMM)
  bf16* Opart = (bf16*)(ws + 26 * MB);   // 16MB bf16 partials (26..42)
  bf16* wqt   = (bf16*)(ws + 26 * MB);   // 2MB each, dead after QKV GEMM
  bf16* wkt   = (bf16*)(ws + 28 * MB);   //   (overlaid by Opart afterwards)
  bf16* wvt   = (bf16*)(ws + 30 * MB);
  float* Lpart = (float*)(ws + 58 * MB); // 512KB row-sum partials

  transpose_w<<<dim3(16, 16, 4), 256, 0, stream>>>(Wq, Wk, Wv, Wo, wqt, wkt, wvt, wot);
  gemm_qkv<<<dim3(32, 8, 3), 256, 0, stream>>>(query, key_, value, wqt, wkt, wvt,
                                               qh, kh, vperm);
  attn_kernel<<<dim3(32, 16, 2), 256, 0, stream>>>(qh, kh, vperm, mask, Opart, Lpart);
  gemm_out<<<dim3(64, 8), 256, 0, stream>>>(Opart, Lpart, wot, (float*)d_out);
}

// Round 6
// 209.602 us; speedup vs baseline: 1.0753x; 1.0753x over previous
//
#include <hip/hip_runtime.h>
#include <hip/hip_bf16.h>
#include <stdint.h>

typedef __bf16 bf16;
typedef __bf16 bf16x8 __attribute__((ext_vector_type(8)));
typedef __bf16 bf16x4 __attribute__((ext_vector_type(4)));
typedef float  f32x4  __attribute__((ext_vector_type(4)));
typedef float  f32x16 __attribute__((ext_vector_type(16)));

#define S_LEN  2048
#define NH     16
#define DKV    64
#define DMODEL 1024
#define LOG2E  1.4426950408889634f

// raw barrier + counted waits: keep loads in flight across barriers (T3/T4).
#define SBAR()       __builtin_amdgcn_s_barrier()
#define SFENCE()     __builtin_amdgcn_sched_barrier(0)
#define WAIT_VM(N)   asm volatile("s_waitcnt vmcnt(" #N ")" ::: "memory")
#define WAIT_LGKM0() asm volatile("s_waitcnt lgkmcnt(0)" ::: "memory")

// ---------------------------------------------------------------------------
// async global->LDS 16B copy. LDS dest is wave-uniform base + lane*16.
// ---------------------------------------------------------------------------
__device__ __forceinline__ void async_load16(const void* g, void* l) {
  __builtin_amdgcn_global_load_lds(
      (const __attribute__((address_space(1))) uint32_t*)(uintptr_t)g,
      (__attribute__((address_space(3))) uint32_t*)(uintptr_t)l,
      16, 0, 0);
}

// ---------------------------------------------------------------------------
// Transpose-cast W [K=1024][N=1024] fp32 -> Wt bf16 [N][K].
// v2: 64x64 tiles, vectorized global I/O (f32x4 loads, bf16x8 stores).
// grid (16,16,4), block 256.
// ---------------------------------------------------------------------------
__global__ void transpose_w(const float* __restrict__ W0, const float* __restrict__ W1,
                            const float* __restrict__ W2, const float* __restrict__ W3,
                            bf16* __restrict__ T0, bf16* __restrict__ T1,
                            bf16* __restrict__ T2, bf16* __restrict__ T3)
{
  int z = blockIdx.z;
  const float* W = (z == 0) ? W0 : (z == 1) ? W1 : (z == 2) ? W2 : W3;
  bf16* T = (z == 0) ? T0 : (z == 1) ? T1 : (z == 2) ? T2 : T3;
  __shared__ float tile[64][65];         // +1 pad: write-phase reads 2-way max
  int n0 = blockIdx.x * 64, k0 = blockIdx.y * 64;
  int tid = threadIdx.x;

  // load: rows k0..k0+63 x cols n0..n0+63, f32x4 coalesced (256B/row-wave)
  int c4 = (tid & 15) * 4;
  int rr = tid >> 4;                     // 0..15
  for (int g = 0; g < 4; ++g) {
    int k = g * 16 + rr;
    f32x4 v = *(const f32x4*)(W + (size_t)(k0 + k) * DMODEL + n0 + c4);
    tile[k][c4] = v[0]; tile[k][c4 + 1] = v[1];
    tile[k][c4 + 2] = v[2]; tile[k][c4 + 3] = v[3];
  }
  __syncthreads();

  // store: T row n = 64 bf16 = 8 lanes x bf16x8 (128B/row)
  int kc = tid & 7, rn2 = tid >> 3;      // rn2 0..31
  for (int pass = 0; pass < 2; ++pass) {
    int rn = pass * 32 + rn2;
    bf16x8 o;
    for (int w = 0; w < 8; ++w) o[w] = (bf16)tile[kc * 8 + w][rn];
    *(bf16x8*)(T + (size_t)(n0 + rn) * DMODEL + k0 + kc * 8) = o;
  }
}

// ---------------------------------------------------------------------------
// QKV GEMM: fused fp32->bf16 cast on A; 128x128 tile, BK=64. (round-4 winner;
// z==2 epilogue writes vperm layout [bh][tile][p][d][8] for b128 PV reads.)
// grid (m=32, n=8, z=3) = 768 blocks = 3/CU; LDS 48KB.
// ---------------------------------------------------------------------------
__global__ __launch_bounds__(256) void gemm_qkv(
    const float* __restrict__ Aq, const float* __restrict__ Ak, const float* __restrict__ Av,
    const bf16* __restrict__ Bq, const bf16* __restrict__ Bk, const bf16* __restrict__ Bv,
    bf16* __restrict__ Cq, bf16* __restrict__ Ck, bf16* __restrict__ Cv)
{
  __shared__ __align__(16) char smem[49152];   // As 16K [128][64] + Bs0/Bs1 16K each
  bf16* As  = (bf16*)smem;
  bf16* Bs0 = (bf16*)(smem + 16384);
  bf16* Bs1 = (bf16*)(smem + 32768);
  bf16* Ls  = (bf16*)smem;               // epilogue overlay [128][132] = 33.8KB

  const int z = blockIdx.z;
  const float* A = (z == 0) ? Aq : (z == 1) ? Ak : Av;
  const bf16* Bt = (z == 0) ? Bq : (z == 1) ? Bk : Bv;
  bf16* C        = (z == 0) ? Cq : (z == 1) ? Ck : Cv;

  const int m0 = blockIdx.x * 128;       // m on x: XCD-local A reuse
  const int n0 = blockIdx.y * 128;
  const int tid = threadIdx.x;
  const int lane = tid & 63;
  const int wave = tid >> 6;
  const int wm = (wave >> 1) * 64;       // wave output: 64x64
  const int wn = (wave & 1) * 64;
  const int row = lane & 15;
  const int quad = lane >> 4;

  f32x4 acc[4][4];
  for (int i = 0; i < 4; ++i)
    for (int j = 0; j < 4; ++j) acc[i][j] = (f32x4){0.f, 0.f, 0.f, 0.f};

  const int arc = tid & 7;
  const int arr = tid >> 3;              // 0..31
  const float* Ap0 = A + (size_t)(m0 +  0 + arr) * DMODEL + arc * 8;
  const float* Ap1 = A + (size_t)(m0 + 32 + arr) * DMODEL + arc * 8;
  const float* Ap2 = A + (size_t)(m0 + 64 + arr) * DMODEL + arc * 8;
  const float* Ap3 = A + (size_t)(m0 + 96 + arr) * DMODEL + arc * 8;

  auto stageB = [&](int kt, bf16* Bsel) {
    const int kk = kt << 6;
    for (int j = 0; j < 4; ++j) {
      int base = j * 256 + wave * 64;
      int idx = base + lane;
      int r = idx >> 3;
      int cc = (idx & 7) ^ (r & 7);
      async_load16(Bt + (size_t)(n0 + r) * DMODEL + kk + cc * 8,
                   (char*)Bsel + (size_t)base * 16);
    }
  };

  f32x4 av[4][2];
  av[0][0] = *(const f32x4*)(Ap0); av[0][1] = *(const f32x4*)(Ap0 + 4);
  av[1][0] = *(const f32x4*)(Ap1); av[1][1] = *(const f32x4*)(Ap1 + 4);
  av[2][0] = *(const f32x4*)(Ap2); av[2][1] = *(const f32x4*)(Ap2 + 4);
  av[3][0] = *(const f32x4*)(Ap3); av[3][1] = *(const f32x4*)(Ap3 + 4);
  SFENCE();
  stageB(0, Bs0);
  SFENCE();

  for (int kt = 0; kt < 16; ++kt) {
    bf16* Bcur = (kt & 1) ? Bs1 : Bs0;
    bf16* Bnxt = (kt & 1) ? Bs0 : Bs1;
    if (kt < 15) stageB(kt + 1, Bnxt);
#pragma unroll
    for (int g = 0; g < 4; ++g) {
      bf16x8 o;
      for (int w = 0; w < 4; ++w) { o[w] = (bf16)av[g][0][w]; o[w + 4] = (bf16)av[g][1][w]; }
      int r = g * 32 + arr;              // (r&7)==(arr&7)
      *(bf16x8*)(As + r * 64 + ((arc ^ (arr & 7)) << 3)) = o;
    }
    if (kt < 15) {
      const int kn = (kt + 1) << 6;
      av[0][0] = *(const f32x4*)(Ap0 + kn); av[0][1] = *(const f32x4*)(Ap0 + kn + 4);
      av[1][0] = *(const f32x4*)(Ap1 + kn); av[1][1] = *(const f32x4*)(Ap1 + kn + 4);
      av[2][0] = *(const f32x4*)(Ap2 + kn); av[2][1] = *(const f32x4*)(Ap2 + kn + 4);
      av[3][0] = *(const f32x4*)(Ap3 + kn); av[3][1] = *(const f32x4*)(Ap3 + kn + 4);
    }
    SFENCE();
    if (kt < 15) { WAIT_VM(12); }        // guard: B(kt+1)4 + av(kt+1)8 in flight
    else         { WAIT_VM(0); }
    WAIT_LGKM0();
    SBAR();
    SFENCE();
    for (int ks = 0; ks < 2; ++ks) {
      bf16x8 af[4], bfr[4];
      for (int i = 0; i < 4; ++i) {
        int rr = wm + i * 16 + row;
        af[i] = *(const bf16x8*)(As + rr * 64 + (((quad + ks * 4) ^ (rr & 7)) << 3));
      }
      for (int j = 0; j < 4; ++j) {
        int rr = wn + j * 16 + row;
        bfr[j] = *(const bf16x8*)(Bcur + rr * 64 + (((quad + ks * 4) ^ (rr & 7)) << 3));
      }
      for (int i = 0; i < 4; ++i)
        for (int j = 0; j < 4; ++j)
          acc[i][j] = __builtin_amdgcn_mfma_f32_16x16x32_bf16(af[i], bfr[j], acc[i][j], 0, 0, 0);
    }
    SFENCE();
    SBAR();
  }

  if (z != 2) {
    const int bq = m0 >> 11;
    __syncthreads();
    for (int i = 0; i < 4; ++i)
      for (int j = 0; j < 4; ++j)
        for (int r = 0; r < 4; ++r)
          Ls[(wm + i * 16 + quad * 4 + r) * 132 + wn + j * 16 + row] = (bf16)acc[i][j][r];
    __syncthreads();
    for (int u = 0; u < 8; ++u) {
      int cc = u * 256 + tid;
      int rloc = cc >> 4, c8 = (cc & 15) * 8;
      int s = (m0 + rloc) & 2047;
      int gn = n0 + c8;
      int h = gn >> 6, d = gn & 63;
      bf16x8 val = *(const bf16x8*)(Ls + rloc * 132 + c8);
      *(bf16x8*)(C + (((size_t)(bq * NH + h)) * S_LEN + s) * DKV + d) = val;
    }
  } else {
    // V permuted for attn PV: [bh][tile=s/64][p][d][slot(8)]
    //   kb=(s&63)>>2, half=(kb>>1)&1, p=(kb&1)+2*((kb>>2)&1)+4*(kb>>3),
    //   slot = half*4 + (s&3). Reader gets {kb_lo, kb_lo+2} pairs contiguously.
    for (int i = 0; i < 4; ++i)
      for (int j = 0; j < 4; ++j) {
        int gm = m0 + wm + i * 16 + quad * 4;    // s base (r=0..3 consecutive)
        int gn = n0 + wn + j * 16 + row;
        int b = gm >> 11, s = gm & 2047;
        int h = gn >> 6,  d = gn & 63;
        int bh = b * NH + h;
        int tile = s >> 6, kb = (s & 63) >> 2;
        int half = (kb >> 1) & 1;
        int p = (kb & 1) + ((kb >> 2) & 1) * 2 + (kb >> 3) * 4;
        bf16x4 t;
        for (int r = 0; r < 4; ++r) t[r] = (bf16)acc[i][j][r];
        *(bf16x4*)(C + ((((size_t)bh * 32 + tile) * 8 + p) * 64 + d) * 8 + half * 4) = t;
      }
  }
}

// ---------------------------------------------------------------------------
// Flash attention: S^T = K*Q^T via 32x32x16 MFMA; P stays in registers.
// v4: keep single-b128 PV fragments (vperm [p][d][8] layout); REVERT the z16
// pinned-zero accumulator (round-5 spill signature: +24MB traffic, all pipes
// idler, VGPR stuck at 64). Plain Sm zero-init as in the 50.3us round-4 build.
// grid (bh=32, q=16, zh=2); LDS 33KB.
// ---------------------------------------------------------------------------
__global__ __launch_bounds__(256, 4) void attn_kernel(
    const bf16* __restrict__ Qh, const bf16* __restrict__ Kh, const bf16* __restrict__ Vperm,
    const float* __restrict__ mask, bf16* __restrict__ Opart, float* __restrict__ Lpart)
{
  __shared__ __align__(16) bf16 Ks[2][64 * 64];    // [kv][d], chunk XOR-swizzled
  __shared__ __align__(16) bf16 Vts[2][64 * 64];   // [p][d][8] (permuted)
  __shared__ __align__(16) float masks2[2][64];

  const int bh = blockIdx.x;
  const int b = bh >> 4;
  const int q0 = blockIdx.y * 128;
  const int zh = blockIdx.z;
  const int tid = threadIdx.x;
  const int lane = tid & 63;
  const int wave = tid >> 6;
  const int ln = lane & 31;
  const int hi = lane >> 5;
  const float SC2 = 0.125f * LOG2E;

  const int qg = q0 + wave * 32 + ln;
  bf16x8 qf[4];
  {
    const bf16* qrow = Qh + ((size_t)bh * S_LEN + qg) * DKV;
    for (int c = 0; c < 4; ++c)
      qf[c] = *(const bf16x8*)(qrow + c * 16 + hi * 8);
  }

  auto stage = [&](int it, int buf) {
    const int kv0 = zh * 1024 + it * 64;
    float mval = 0.f;
    if (tid < 64) mval = mask[b * S_LEN + kv0 + tid];   // issued first
    const bf16* vtile = Vperm + ((size_t)bh * 32 + (kv0 >> 6)) * 4096;
    for (int j = 0; j < 2; ++j) {
      int base = j * 256 + wave * 64;
      int idx = base + lane;
      int r = idx >> 3;
      int cc = (idx & 7) ^ (r & 7);
      async_load16(Kh + ((size_t)bh * S_LEN + kv0 + r) * DKV + cc * 8,
                   (char*)Ks[buf] + (size_t)base * 16);
      async_load16(vtile + (size_t)idx * 8,
                   (char*)Vts[buf] + (size_t)base * 16);
    }
    if (tid < 64) masks2[buf][tid] = mval * LOG2E;
  };

  f32x16 O[2];
  for (int nb = 0; nb < 2; ++nb)
    for (int i = 0; i < 16; ++i) O[nb][i] = 0.f;
  float lsum = 0.f;

  stage(0, 0);                                  // prologue

  for (int it = 0; it < 16; ++it) {
    const int cur = it & 1;
    if (it < 15) stage(it + 1, cur ^ 1);
    SFENCE();
    if (it < 15) { WAIT_VM(4); }                // KV(it) landed; KV(it+1) in flight
    else         { WAIT_VM(0); }
    WAIT_LGKM0();
    SBAR();
    SFENCE();

    // S^T = K * Q^T  (A = K[kv][d], m=kv: 2 m-blocks; B = qf; 4 k-chunks)
    f32x16 Sm[2];
    for (int i = 0; i < 16; ++i) { Sm[0][i] = 0.f; Sm[1][i] = 0.f; }
    for (int c = 0; c < 4; ++c) {
      bf16x8 k0 = *(const bf16x8*)(Ks[cur] + ln * 64        + (((2 * c + hi) ^ (ln & 7)) << 3));
      bf16x8 k1 = *(const bf16x8*)(Ks[cur] + (32 + ln) * 64 + (((2 * c + hi) ^ (ln & 7)) << 3));
      Sm[0] = __builtin_amdgcn_mfma_f32_32x32x16_bf16(k0, qf[c], Sm[0], 0, 0, 0);
      Sm[1] = __builtin_amdgcn_mfma_f32_32x32x16_bf16(k1, qf[c], Sm[1], 0, 0, 0);
    }

    // P = exp2(S*SC2 + mask*LOG2E) in registers -> PV (one b128 per fragment)
    for (int cg = 0; cg < 4; ++cg) {
      int mb = cg >> 1, g = cg & 1;
      int koff = 32 * mb + 16 * g + 4 * hi;
      f32x4 mklo = *(const f32x4*)(&masks2[cur][koff]);
      f32x4 mkhi = *(const f32x4*)(&masks2[cur][koff + 8]);
      bf16x8 ap;
      float ls0 = 0.f;
      for (int u = 0; u < 4; ++u) {
        float p = __builtin_amdgcn_exp2f(Sm[mb][g * 8 + u] * SC2 + mklo[u]);
        ls0 += p; ap[u] = (bf16)p;
      }
      for (int u = 0; u < 4; ++u) {
        float p = __builtin_amdgcn_exp2f(Sm[mb][g * 8 + 4 + u] * SC2 + mkhi[u]);
        ls0 += p; ap[4 + u] = (bf16)p;
      }
      lsum += ls0;
      int p = hi + 2 * g + 4 * mb;              // pair index in V layout
      for (int nb = 0; nb < 2; ++nb) {
        int d = nb * 32 + ln;
        bf16x8 bv = *(const bf16x8*)(Vts[cur] + ((size_t)p * 64 + d) * 8);
        O[nb] = __builtin_amdgcn_mfma_f32_32x32x16_bf16(ap, bv, O[nb], 0, 0, 0);
      }
    }
    SFENCE();
    SBAR();
  }

  // partial row sums
  float lt = lsum + __shfl_xor(lsum, 32, 64);
  if (lane < 32)
    Lpart[((size_t)zh * 32 + bh) * S_LEN + q0 + wave * 32 + ln] = lt;

  // partial O (un-normalized, bf16): Opart[zh][bh][q][d]
  bf16* ob = Opart + (((size_t)zh * 32 + bh) * S_LEN) * DKV;
  for (int g = 0; g < 4; ++g)
    for (int nb = 0; nb < 2; ++nb)
      for (int j = 0; j < 4; ++j) {
        int qrow = q0 + wave * 32 + j + 8 * g + 4 * hi;
        ob[(size_t)qrow * DKV + nb * 32 + ln] = (bf16)O[nb][g * 4 + j];
      }
}

// ---------------------------------------------------------------------------
// Out-GEMM v2: 64x128 tile; wave output 32x64 -> 16 MFMA / 12 b128.
// Fused combine+normalize on A; depth-1 Opart reg prefetch; B dbuf + counted
// vmcnt. grid (m=64, n=8) = 512 blocks -> 2/CU; LDS 45KB.
// ---------------------------------------------------------------------------
__global__ __launch_bounds__(256) void gemm_out(
    const bf16* __restrict__ Opart, const float* __restrict__ Lpart,
    const bf16* __restrict__ Wot, float* __restrict__ Cout)
{
  __shared__ __align__(16) bf16 As[64 * 64];       // 8KB swizzled
  __shared__ __align__(16) bf16 Bs[2][128 * 64];   // 32KB swizzled, dbuf
  __shared__ float rinv[NH * 64];                  // 4KB

  const int m0 = blockIdx.x * 64;        // m on x: XCD-local Opart reuse
  const int n0 = blockIdx.y * 128;
  const int tid = threadIdx.x;
  const int lane = tid & 63;
  const int wave = tid >> 6;
  const int wm = (wave >> 1) * 32;
  const int wn = (wave & 1) * 64;
  const int row = lane & 15;
  const int quad = lane >> 4;
  const int b = m0 >> 11;
  const int s0 = m0 & 2047;

  // per-block row-sum reciprocals: all 16 heads x 64 rows
  for (int u = 0; u < 4; ++u) {
    int idx = u * 256 + tid;
    int h = idx >> 6, r = idx & 63;
    float l = Lpart[(size_t)(b * NH + h) * S_LEN + s0 + r]
            + Lpart[(size_t)(32 + b * NH + h) * S_LEN + s0 + r];
    rinv[idx] = 1.0f / l;
  }
  SFENCE();

  f32x4 acc[2][4];
  for (int i = 0; i < 2; ++i)
    for (int j = 0; j < 4; ++j) acc[i][j] = (f32x4){0.f, 0.f, 0.f, 0.f};

  const int arc = tid & 7;               // chunk col
  const int arr = tid >> 3;              // row 0..31 (second row adds 32)
  const size_t HSTEP = (size_t)S_LEN * DKV;        // per-head stride
  const size_t ZSTEP = (size_t)32 * S_LEN * DKV;   // zh stride
  const bf16* Oa = Opart + ((size_t)(b * NH) * S_LEN + s0 + arr) * DKV + arc * 8;
  const bf16* Ob = Oa + (size_t)32 * DKV;          // row arr+32

  auto stageB = [&](int kt, int buf) {
    for (int j = 0; j < 4; ++j) {
      int base = j * 256 + wave * 64;
      int idx = base + lane;
      int r = idx >> 3;
      int cc = (idx & 7) ^ (r & 7);
      async_load16(Wot + (size_t)(n0 + r) * DMODEL + kt * 64 + cc * 8,
                   (char*)Bs[buf] + (size_t)base * 16);
    }
  };

  // prologue: h(0)[4] -> B(0)[4]
  bf16x8 h00 = *(const bf16x8*)(Oa);
  bf16x8 h01 = *(const bf16x8*)(Oa + ZSTEP);
  bf16x8 h10 = *(const bf16x8*)(Ob);
  bf16x8 h11 = *(const bf16x8*)(Ob + ZSTEP);
  SFENCE();
  stageB(0, 0);
  SFENCE();
  WAIT_LGKM0();                          // rinv ds_writes visible
  SBAR();                                // publish rinv (no vmcnt drain)

  for (int kt = 0; kt < 16; ++kt) {      // kt == head index (BK=64 == DKV)
    const int cur = kt & 1;
    if (kt < 15) stageB(kt + 1, cur ^ 1);
    {
      float rv  = rinv[kt * 64 + arr];
      float rv2 = rinv[kt * 64 + 32 + arr];
      bf16x8 o;
      for (int w = 0; w < 8; ++w)
        o[w] = (bf16)(((float)h00[w] + (float)h01[w]) * rv);
      *(bf16x8*)(As + arr * 64 + ((arc ^ (arr & 7)) << 3)) = o;
      for (int w = 0; w < 8; ++w)
        o[w] = (bf16)(((float)h10[w] + (float)h11[w]) * rv2);
      *(bf16x8*)(As + (32 + arr) * 64 + ((arc ^ (arr & 7)) << 3)) = o;  // (32+arr)&7==arr&7
    }
    if (kt < 15) {                       // prefetch h(kt+1) during MFMA
      const size_t off = (size_t)(kt + 1) * HSTEP;
      h00 = *(const bf16x8*)(Oa + off);
      h01 = *(const bf16x8*)(Oa + off + ZSTEP);
      h10 = *(const bf16x8*)(Ob + off);
      h11 = *(const bf16x8*)(Ob + off + ZSTEP);
    }
    SFENCE();
    if (kt < 15) { WAIT_VM(8); }         // B(kt+1)4 + h(kt+1)4 in flight
    else         { WAIT_VM(0); }
    WAIT_LGKM0();
    SBAR();
    SFENCE();
    for (int ks = 0; ks < 2; ++ks) {
      bf16x8 af[2], bfr[4];
      for (int i = 0; i < 2; ++i) {
        int rr = wm + i * 16 + row;
        af[i] = *(const bf16x8*)(As + rr * 64 + (((quad + ks * 4) ^ (rr & 7)) << 3));
      }
      for (int j = 0; j < 4; ++j) {
        int rr = wn + j * 16 + row;
        bfr[j] = *(const bf16x8*)(Bs[cur] + rr * 64 + (((quad + ks * 4) ^ (rr & 7)) << 3));
      }
      for (int i = 0; i < 2; ++i)
        for (int j = 0; j < 4; ++j)
          acc[i][j] = __builtin_amdgcn_mfma_f32_16x16x32_bf16(af[i], bfr[j], acc[i][j], 0, 0, 0);
    }
    SFENCE();
    SBAR();
  }

  for (int i = 0; i < 2; ++i)
    for (int j = 0; j < 4; ++j)
      for (int r = 0; r < 4; ++r) {
        int gm = m0 + wm + i * 16 + quad * 4 + r;
        int gn = n0 + wn + j * 16 + row;
        Cout[(size_t)gm * DMODEL + gn] = acc[i][j][r];
      }
}

// ---------------------------------------------------------------------------
extern "C" void kernel_launch(void* const* d_in, const int* in_sizes, int n_in,
                              void* d_out, int out_size, void* d_ws, size_t ws_size,
                              hipStream_t stream)
{
  const float* query = (const float*)d_in[0];
  const float* key_  = (const float*)d_in[1];
  const float* value = (const float*)d_in[2];
  const float* mask  = (const float*)d_in[3];
  const float* Wq = (const float*)d_in[4];
  const float* Wk = (const float*)d_in[5];
  const float* Wv = (const float*)d_in[6];
  const float* Wo = (const float*)d_in[7];

  char* ws = (char*)d_ws;
  const size_t MB = (size_t)1 << 20;
  bf16* qh    = (bf16*)(ws + 0 * MB);    // 8MB [B,NH,S,DKV]
  bf16* kh    = (bf16*)(ws + 8 * MB);    // 8MB [B,NH,S,DKV]
  bf16* vperm = (bf16*)(ws + 16 * MB);   // 8MB PV-permuted V
  bf16* wot   = (bf16*)(ws + 24 * MB);   // 2MB (live until out-GEMM)
  bf16* Opart = (bf16*)(ws + 26 * MB);   // 16MB bf16 partials (26..42)
  bf16* wqt   = (bf16*)(ws + 26 * MB);   // 2MB each, dead after QKV GEMM
  bf16* wkt   = (bf16*)(ws + 28 * MB);   //   (overlaid by Opart afterwards)
  bf16* wvt   = (bf16*)(ws + 30 * MB);
  float* Lpart = (float*)(ws + 58 * MB); // 512KB row-sum partials

  transpose_w<<<dim3(16, 16, 4), 256, 0, stream>>>(Wq, Wk, Wv, Wo, wqt, wkt, wvt, wot);
  gemm_qkv<<<dim3(32, 8, 3), 256, 0, stream>>>(query, key_, value, wqt, wkt, wvt,
                                               qh, kh, vperm);
  attn_kernel<<<dim3(32, 16, 2), 256, 0, stream>>>(qh, kh, vperm, mask, Opart, Lpart);
  gemm_out<<<dim3(64, 8), 256, 0, stream>>>(Opart, Lpart, wot, (float*)d_out);
}